// Round 16
// baseline (595.294 us; speedup 1.0000x reference)
//
#include <hip/hip_runtime.h>
#include <hip/hip_bf16.h>

typedef __bf16 bf16;
typedef __bf16 bf16x8 __attribute__((ext_vector_type(8)));
typedef __bf16 bf16x4v __attribute__((ext_vector_type(4)));
typedef float f32x4 __attribute__((ext_vector_type(4)));
typedef unsigned int u32;
typedef u32 u32x4 __attribute__((ext_vector_type(4)));

#define DEV static __device__ __forceinline__
#define SB0 __builtin_amdgcn_sched_barrier(0)
#define BAR __builtin_amdgcn_s_barrier()
#define LGKM0 asm volatile("s_waitcnt lgkmcnt(0)" ::: "memory")
#define PRIO1 __builtin_amdgcn_s_setprio(1)
#define PRIO0 __builtin_amdgcn_s_setprio(0)

DEV void gll16(const void* g, void* l) {
  __builtin_amdgcn_global_load_lds((__attribute__((address_space(1))) void*)g,
                                   (__attribute__((address_space(3))) void*)l,
                                   16, 0, 0);
}

DEV bf16 tobf(float f) { return (bf16)f; }

DEV u32 cvtpk(float lo, float hi) {
  u32 r;
  asm("v_cvt_pk_bf16_f32 %0, %1, %2" : "=v"(r) : "v"(lo), "v"(hi));
  return r;
}

// ---------------- cast f32 -> bf16 (x4 vectorized) ----------------
__global__ void cast_f2b_kernel(const float* __restrict__ in, bf16* __restrict__ out, int n4) {
  int i = blockIdx.x * 256 + threadIdx.x;
  if (i < n4) {
    const float4 v = ((const float4*)in)[i];
    bf16x4v o;
    o[0] = tobf(v.x); o[1] = tobf(v.y); o[2] = tobf(v.z); o[3] = tobf(v.w);
    ((bf16x4v*)out)[i] = o;
  }
}

// ------------- transpose-pack: out[N][K] bf16 = in[K][N] f32 * scale -------------
__global__ __launch_bounds__(256)
void tpack_kernel(const float* __restrict__ in, bf16* __restrict__ out,
                  int K, int N, int in_hs, int out_hs, float scale) {
  __shared__ float tile[32][33];
  const int k0 = blockIdx.x << 5, n0 = blockIdx.y << 5;
  const float* ip = in + (size_t)blockIdx.z * in_hs;
  bf16* op = out + (size_t)blockIdx.z * out_hs;
  const int tx = threadIdx.x & 31, ty = threadIdx.x >> 5;
#pragma unroll
  for (int r = 0; r < 4; ++r)
    tile[ty * 4 + r][tx] = ip[(size_t)(k0 + ty * 4 + r) * N + n0 + tx];
  __syncthreads();
#pragma unroll
  for (int r = 0; r < 4; ++r)
    op[(size_t)(n0 + ty * 4 + r) * K + k0 + tx] = tobf(tile[tx][ty * 4 + r] * scale);
}

// ---------------- bias scale copy ----------------
__global__ void bscale_kernel(const float* __restrict__ in, float* __restrict__ out, int n, float s) {
  int i = blockIdx.x * 256 + threadIdx.x;
  if (i < n) out[i] = in[i] * s;
}

// 2D L2 group swizzle (4x4 blocks per group) after XCD chunking.
DEV void tile_map(int bid, int nwg, int nbx, int& tm, int& tn) {
  bid = (bid & 7) * (nwg >> 3) + (bid >> 3);     // XCD chunk
  const int gid = bid >> 4, g4 = bid & 15;
  const int gpr = nbx >> 2;
  tm = ((gid / gpr) << 2) | (g4 >> 2);
  tn = ((gid % gpr) << 2) | (g4 & 3);
}

// Per-lane swizzled LDS read base (bits 4-6 XOR is lane-constant since all
// fragment rows are R0 + l15 with R0 % 16 == 0):
DEV int lane_base(int l15, int l4, int kk) {
  return (l15 << 7) + (((kk << 6) | (l4 << 4)) ^ ((l15 & 7) << 4));
}

// =====================================================================
// gemm8 — the single GEMM workhorse (r15 consolidation: gemmP retired;
// its 8-phase/128-acc structure chronically spilled at the 256-reg
// structural cap while matching gemm8's 747 TF).
// BM=256 BN=128 BK=64, 512 thr = 8 waves (4M x 2N),
// 3 LDS buffers (144 KiB -> 1 block/CU), counted vmcnt(6), setprio.
// LDS reads: direct (char*)sA + int offsets (r13: pointer rotation ->
// flat_load on LDS destroys vmcnt accounting).
// EPI 0: bf16 acc+bias(col)     1: f32 acc+bias+resid
// EPI 2: bf16 relu(acc+bias)    4: fused QK segs (N=2048, both rowmajor)
// EPI 6: bf16 acc+bias(ROW)  (V^T GEMM)
// =====================================================================
template<int EPI>
__global__ __launch_bounds__(512, 1)
void gemm8(const bf16* __restrict__ A, const bf16* __restrict__ W,
           const float* __restrict__ bias, const float* __restrict__ resid,
           void* __restrict__ outv, int M, int N, int K) {
  __shared__ bf16 sA[3][256 * 64];
  __shared__ bf16 sB[3][128 * 64];
  const int nbx = N >> 7;
  const int nwg = (M >> 8) * nbx;
  int tm, tn;
  tile_map((int)blockIdx.x, nwg, nbx, tm, tn);
  const int tid = threadIdx.x;
  const int lane = tid & 63;
  const int w = tid >> 6;
  const int wr = w >> 1, wc = w & 1;           // 4M x 2N waves
  const int l15 = lane & 15, l4 = lane >> 4;

  const bf16* Abase = A + (size_t)(tm * 256) * K;
  const bf16* Bbase = W + (size_t)(tn * 128) * K;

  const bf16* gAsrc[4];
  int loffA[4];
#pragma unroll
  for (int j = 0; j < 4; ++j) {
    int g = tid + (j << 9);
    int row = g >> 3;
    int sc = ((g & 7) ^ (row & 7)) << 3;
    gAsrc[j] = Abase + (size_t)row * K + sc;
    loffA[j] = g << 4;
  }
  const bf16* gBsrc[2];
  int loffB[2];
#pragma unroll
  for (int j = 0; j < 2; ++j) {
    int g = tid + (j << 9);
    int row = g >> 3;
    int sc = ((g & 7) ^ (row & 7)) << 3;
    gBsrc[j] = Bbase + (size_t)row * K + sc;
    loffB[j] = g << 4;
  }

  int obA[2], obB[2];
#pragma unroll
  for (int kk = 0; kk < 2; ++kk) {
    obA[kk] = wr * 8192 + lane_base(l15, l4, kk);
    obB[kk] = wc * 8192 + lane_base(l15, l4, kk);
  }

  f32x4 acc[4][4] = {};
  const int nt = K >> 6;

  auto stageA = [&](int buf, int t) {
    const int db = buf << 15;                   // sA buffer stride 32768 B
    const size_t so = (size_t)t << 6;
#pragma unroll
    for (int j = 0; j < 4; ++j) gll16(gAsrc[j] + so, (char*)sA + db + loffA[j]);
  };
  auto stageB = [&](int buf, int t) {
    const int db = buf << 14;                   // sB buffer stride 16384 B
    const size_t so = (size_t)t << 6;
#pragma unroll
    for (int j = 0; j < 2; ++j) gll16(gBsrc[j] + so, (char*)sB + db + loffB[j]);
  };

  stageA(0, 0); stageB(0, 0);
  stageA(1, 1 < nt ? 1 : 0); stageB(1, 1 < nt ? 1 : 0);
  SB0;
  asm volatile("s_waitcnt vmcnt(6)" ::: "memory");
  BAR;

  int c = 0;
  for (int t = 0; t < nt; ++t) {
    const int sb = (c >= 1) ? c - 1 : 2;       // (t+2)%3
    const int ts = (t + 2 < nt) ? t + 2 : nt - 1;
    const int aOff = c << 15, bOff = c << 14;
    bf16x8 af[4][2], bfr[4][2];
#pragma unroll
    for (int mi = 0; mi < 4; ++mi)
#pragma unroll
      for (int kk = 0; kk < 2; ++kk)
        af[mi][kk] = *(const bf16x8*)((const char*)sA + aOff + obA[kk] + (mi << 11));
#pragma unroll
    for (int ni = 0; ni < 2; ++ni)
#pragma unroll
      for (int kk = 0; kk < 2; ++kk)
        bfr[ni][kk] = *(const bf16x8*)((const char*)sB + bOff + obB[kk] + (ni << 11));
    stageA(sb, ts);
    SB0; BAR; LGKM0; SB0; PRIO1;
#pragma unroll
    for (int mi = 0; mi < 4; ++mi)
#pragma unroll
      for (int ni = 0; ni < 2; ++ni)
#pragma unroll
        for (int kk = 0; kk < 2; ++kk)
          acc[mi][ni] = __builtin_amdgcn_mfma_f32_16x16x32_bf16(af[mi][kk], bfr[ni][kk],
                                                                acc[mi][ni], 0, 0, 0);
    PRIO0; SB0; BAR;
#pragma unroll
    for (int ni = 2; ni < 4; ++ni)
#pragma unroll
      for (int kk = 0; kk < 2; ++kk)
        bfr[ni][kk] = *(const bf16x8*)((const char*)sB + bOff + obB[kk] + (ni << 11));
    stageB(sb, ts);
    SB0;
    asm volatile("s_waitcnt vmcnt(6)" ::: "memory");
    BAR; LGKM0; SB0; PRIO1;
#pragma unroll
    for (int mi = 0; mi < 4; ++mi)
#pragma unroll
      for (int ni = 2; ni < 4; ++ni)
#pragma unroll
        for (int kk = 0; kk < 2; ++kk)
          acc[mi][ni] = __builtin_amdgcn_mfma_f32_16x16x32_bf16(af[mi][kk], bfr[ni][kk],
                                                                acc[mi][ni], 0, 0, 0);
    PRIO0; SB0; BAR;
    c = (c == 2) ? 0 : c + 1;
  }

  const int row0 = tm * 256 + wr * 64 + (l4 << 2);
  const int col0 = tn * 128 + wc * 64 + l15;
#pragma unroll
  for (int ni = 0; ni < 4; ++ni) {
    const int col = col0 + (ni << 4);
    const float bv = (EPI == 6) ? 0.f : bias[col];
#pragma unroll
    for (int mi = 0; mi < 4; ++mi) {
      const int rr = row0 + (mi << 4);
      f32x4 v = acc[mi][ni];
      if (EPI == 0) {
        bf16* out = (bf16*)outv;
#pragma unroll
        for (int r = 0; r < 4; ++r) out[(size_t)(rr + r) * N + col] = tobf(v[r] + bv);
      } else if (EPI == 1) {
        float* out = (float*)outv;
#pragma unroll
        for (int r = 0; r < 4; ++r) {
          size_t idx = (size_t)(rr + r) * N + col;
          out[idx] = v[r] + bv + resid[idx];
        }
      } else if (EPI == 2) {
        bf16* out = (bf16*)outv;
#pragma unroll
        for (int r = 0; r < 4; ++r) out[(size_t)(rr + r) * N + col] = tobf(fmaxf(v[r] + bv, 0.f));
      } else if (EPI == 4) { // fused QK segments (1024-col each), both rowmajor
        bf16* out = (bf16*)outv;
        const int seg = col >> 10;
        const int cc = col & 1023;
        bf16* qout = out + (size_t)seg * 8388608;
#pragma unroll
        for (int r = 0; r < 4; ++r) qout[(size_t)(rr + r) * 1024 + cc] = tobf(v[r] + bv);
      } else { // EPI 6: row-indexed bias (V^T GEMM)
        bf16* out = (bf16*)outv;
        const float4 bq = *(const float4*)(bias + rr);
        const float br[4] = {bq.x, bq.y, bq.z, bq.w};
#pragma unroll
        for (int r = 0; r < 4; ++r) out[(size_t)(rr + r) * N + col] = tobf(v[r] + br[r]);
      }
    }
  }
}

// =====================================================================
// Attention (unchanged since r6-core): swapped-QK^T, defer-max,
// in-register P. V^T layout [1024 dk_full][8192 tok].
// =====================================================================
template<bool MASKED>
__global__ __launch_bounds__(256, 2)
void attn_kernel(const bf16* __restrict__ Qp, const bf16* __restrict__ Kp,
                 const bf16* __restrict__ Vt, bf16* __restrict__ Z) {
  __shared__ bf16 sK[2][64 * 64];
  __shared__ bf16 sV[2][64 * 64];
  const int Lk = 1024;
  const int d = blockIdx.x;
  const int bh = d & 127, qb = d >> 7;
  const int b = bh >> 4, h = bh & 15;
  const int q0 = qb << 7;
  const int tid = threadIdx.x, lane = tid & 63, w = tid >> 6;
  const int l15 = lane & 15, l4 = lane >> 4;

  const bf16* Qb = Qp + ((size_t)(b * 1024 + q0 + w * 32)) * 1024 + h * 64;
  bf16x8 qf[2][2];
#pragma unroll
  for (int mi = 0; mi < 2; ++mi)
#pragma unroll
    for (int kk = 0; kk < 2; ++kk)
      qf[mi][kk] = *(const bf16x8*)(Qb + (size_t)((mi << 4) + l15) * 1024 + (kk << 5) + (l4 << 3));

  f32x4 o[4][2] = {};
  float Mr[2] = {-1e30f, -1e30f}, LrP[2] = {0.f, 0.f};

  const bf16* Kb = Kp + ((size_t)b * Lk) * 1024 + h * 64;
  const bf16* Vb = Vt + (size_t)(h * 64) * 8192 + b * 1024;

  auto stage = [&](int buf, int t, bool withV) {
    const int kv0 = t << 6;
#pragma unroll
    for (int j = 0; j < 2; ++j) {
      int g = tid + (j << 8);
      int r = g >> 3;
      int sc = ((g & 7) ^ (r & 7)) << 3;
      gll16(Kb + (size_t)(kv0 + r) * 1024 + sc, &sK[buf][g << 3]);
      if (withV) gll16(Vb + (size_t)r * 8192 + kv0 + sc, &sV[buf][g << 3]);
    }
  };
  auto needPV = [&](int t) -> bool { return !MASKED || ((t << 6) < q0 + 128); };

  const int NT = Lk >> 6;
  stage(0, 0, true);
  __syncthreads();
  int cur = 0;

  for (int t = 0; t < NT; ++t) {
    if (t + 1 < NT) stage(cur ^ 1, t + 1, needPV(t + 1));
    const int kv0 = t << 6;

    f32x4 s[4][2] = {};
#pragma unroll
    for (int n = 0; n < 4; ++n) {
      bf16x8 kf[2];
#pragma unroll
      for (int kk = 0; kk < 2; ++kk) {
        int r = (n << 4) + l15;
        int off = (r << 7) + (kk << 6) + (l4 << 4);
        off ^= (r & 7) << 4;
        kf[kk] = *(const bf16x8*)((const char*)sK[cur] + off);
      }
#pragma unroll
      for (int mi = 0; mi < 2; ++mi)
#pragma unroll
        for (int kk = 0; kk < 2; ++kk)
          s[n][mi] = __builtin_amdgcn_mfma_f32_16x16x32_bf16(kf[kk], qf[mi][kk],
                                                             s[n][mi], 0, 0, 0);
    }

#pragma unroll
    for (int mi = 0; mi < 2; ++mi) {
      float lmax = s[0][mi][0];
#pragma unroll
      for (int n = 0; n < 4; ++n)
#pragma unroll
        for (int r = 0; r < 4; ++r) lmax = fmaxf(lmax, s[n][mi][r]);
      const bool need = (t == 0) || !__all(lmax <= Mr[mi] + 8.f);
      if (need) {
        float tmx = fmaxf(lmax, __shfl_xor(lmax, 16, 64));
        tmx = fmaxf(tmx, __shfl_xor(tmx, 32, 64));
        const float Mn = fmaxf(Mr[mi], tmx);
        const float al = exp2f(Mr[mi] - Mn);
        LrP[mi] *= al;
        Mr[mi] = Mn;
#pragma unroll
        for (int r = 0; r < 4; ++r) {
          float a = __shfl(al, (l4 << 2) + r, 64);
#pragma unroll
          for (int nd = 0; nd < 4; ++nd) o[nd][mi][r] *= a;
        }
      }
      float rs = 0.f;
#pragma unroll
      for (int n = 0; n < 4; ++n)
#pragma unroll
        for (int r = 0; r < 4; ++r) {
          float p = exp2f(s[n][mi][r] - Mr[mi]);
          s[n][mi][r] = p;
          rs += p;
        }
      LrP[mi] += rs;
    }

    if (needPV(t)) {
      const bool needMask = MASKED && (kv0 + 63 > q0 + (w << 5));
      bf16x8 pa[2][2];
#pragma unroll
      for (int mi = 0; mi < 2; ++mi) {
        u32 D0[4], D1[4];
        const int qg = q0 + (w << 5) + (mi << 4) + l15;
#pragma unroll
        for (int n = 0; n < 4; ++n) {
          float pv[4];
#pragma unroll
          for (int r = 0; r < 4; ++r) {
            float p = s[n][mi][r];
            if (needMask) {
              int cg = kv0 + (n << 4) + (l4 << 2) + r;
              if (cg > qg) p = 0.f;
            }
            pv[r] = p;
          }
          D0[n] = cvtpk(pv[0], pv[1]);
          D1[n] = cvtpk(pv[2], pv[3]);
        }
        const int src = l15 + ((lane & 16) << 1);
#pragma unroll
        for (int kk = 0; kk < 2; ++kk) {
          u32 v0 = (lane & 32) ? D0[2 * kk + 1] : D0[2 * kk];
          u32 v1 = (lane & 32) ? D1[2 * kk + 1] : D1[2 * kk];
          u32x4 tw;
          tw[0] = (u32)__shfl((int)v0, src, 64);
          tw[1] = (u32)__shfl((int)v1, src, 64);
          tw[2] = (u32)__shfl((int)v0, src + 16, 64);
          tw[3] = (u32)__shfl((int)v1, src + 16, 64);
          pa[mi][kk] = __builtin_bit_cast(bf16x8, tw);
        }
      }
#pragma unroll
      for (int nd = 0; nd < 4; ++nd) {
        bf16x8 vf[2];
#pragma unroll
        for (int kk = 0; kk < 2; ++kk) {
          int r = (nd << 4) + l15;
          int off = (r << 7) + (kk << 6) + (l4 << 4);
          off ^= (r & 7) << 4;
          vf[kk] = *(const bf16x8*)((const char*)sV[cur] + off);
        }
#pragma unroll
        for (int mi = 0; mi < 2; ++mi)
#pragma unroll
          for (int kk = 0; kk < 2; ++kk)
            o[nd][mi] = __builtin_amdgcn_mfma_f32_16x16x32_bf16(pa[mi][kk], vf[kk],
                                                                o[nd][mi], 0, 0, 0);
      }
    }
    __syncthreads();
    cur ^= 1;
  }

  float inv[2][4];
#pragma unroll
  for (int mi = 0; mi < 2; ++mi) {
    float l = LrP[mi];
    l += __shfl_xor(l, 16, 64);
    l += __shfl_xor(l, 32, 64);
    const float il = 1.f / l;
#pragma unroll
    for (int r = 0; r < 4; ++r) inv[mi][r] = __shfl(il, (l4 << 2) + r, 64);
  }
  bf16* Zb = Z + ((size_t)(b * 1024 + q0 + w * 32)) * 1024 + h * 64;
#pragma unroll
  for (int nd = 0; nd < 4; ++nd)
#pragma unroll
    for (int mi = 0; mi < 2; ++mi)
#pragma unroll
      for (int r = 0; r < 4; ++r)
        Zb[(size_t)((mi << 4) + (l4 << 2) + r) * 1024 + (nd << 4) + l15] =
            tobf(o[nd][mi][r] * inv[mi][r]);
}

// ---------------- LayerNorm over D=1024, one row per block ----------------
__global__ __launch_bounds__(256)
void ln_kernel(const float* __restrict__ in, const float* __restrict__ gw,
               const float* __restrict__ bw, float* __restrict__ outf,
               bf16* __restrict__ outb) {
  const int row = blockIdx.x, tid = threadIdx.x;
  const size_t base = (size_t)row << 10;
  const float4 v = *(const float4*)(in + base + tid * 4);
  float s = v.x + v.y + v.z + v.w;
  float ss = v.x * v.x + v.y * v.y + v.z * v.z + v.w * v.w;
#pragma unroll
  for (int d = 1; d < 64; d <<= 1) { s += __shfl_xor(s, d, 64); ss += __shfl_xor(ss, d, 64); }
  __shared__ float red[8];
  const int w = tid >> 6;
  if ((tid & 63) == 0) { red[w] = s; red[4 + w] = ss; }
  __syncthreads();
  s = red[0] + red[1] + red[2] + red[3];
  ss = red[4] + red[5] + red[6] + red[7];
  const float mu = s * (1.f / 1024.f);
  const float var = ss * (1.f / 1024.f) - mu * mu;
  const float rstd = rsqrtf(var + 1e-5f);
  const float4 g4 = *(const float4*)(gw + tid * 4);
  const float4 b4 = *(const float4*)(bw + tid * 4);
  const float o0 = (v.x - mu) * rstd * g4.x + b4.x;
  const float o1 = (v.y - mu) * rstd * g4.y + b4.y;
  const float o2 = (v.z - mu) * rstd * g4.z + b4.z;
  const float o3 = (v.w - mu) * rstd * g4.w + b4.w;
  if (outf) { float4 of; of.x = o0; of.y = o1; of.z = o2; of.w = o3;
              *(float4*)(outf + base + tid * 4) = of; }
  if (outb) { bf16x4v ob; ob[0] = tobf(o0); ob[1] = tobf(o1); ob[2] = tobf(o2); ob[3] = tobf(o3);
              *(bf16x4v*)(outb + base + tid * 4) = ob; }
}

// =====================================================================
extern "C" void kernel_launch(void* const* d_in, const int* in_sizes, int n_in,
                              void* d_out, int out_size, void* d_ws, size_t ws_size,
                              hipStream_t stream) {
  const float* x   = (const float*)d_in[0];
  const float* enc = (const float*)d_in[1];
  const float* Wq1 = (const float*)d_in[2];
  const float* bq1 = (const float*)d_in[3];
  const float* Wk1 = (const float*)d_in[4];
  const float* bk1 = (const float*)d_in[5];
  const float* Wv1 = (const float*)d_in[6];
  const float* bv1 = (const float*)d_in[7];
  const float* Wo1 = (const float*)d_in[8];
  const float* bo1 = (const float*)d_in[9];
  const float* Wq2 = (const float*)d_in[10];
  const float* bq2 = (const float*)d_in[11];
  const float* Wk2 = (const float*)d_in[12];
  const float* bk2 = (const float*)d_in[13];
  const float* Wv2 = (const float*)d_in[14];
  const float* bv2 = (const float*)d_in[15];
  const float* Wo2 = (const float*)d_in[16];
  const float* bo2 = (const float*)d_in[17];
  const float* W1  = (const float*)d_in[18];
  const float* b1  = (const float*)d_in[19];
  const float* W2  = (const float*)d_in[20];
  const float* b2  = (const float*)d_in[21];
  const float* g1  = (const float*)d_in[22];
  const float* be1 = (const float*)d_in[23];
  const float* g2  = (const float*)d_in[24];
  const float* be2 = (const float*)d_in[25];
  const float* g3  = (const float*)d_in[26];
  const float* be3 = (const float*)d_in[27];

  char* ws = (char*)d_ws;
  size_t off = 0;
  auto alloc = [&](size_t bytes) { char* p = ws + off; off += (bytes + 255) & ~(size_t)255; return p; };
  const size_t ACT = (size_t)8 * 1024 * 1024 * 2;  // 16 MB: bf16 [8192][1024]
  const float QSC = 0.125f * 1.44269504088896f;    // fold 1/sqrt(DK) * log2(e)

  bf16* xb     = (bf16*)alloc(ACT);
  bf16* encb   = (bf16*)alloc(ACT);
  bf16* Wqk1t  = (bf16*)alloc((size_t)2048 * 1024 * 2);  // [Wq1|Wk1]^T
  bf16* Wv1t   = (bf16*)alloc((size_t)1024 * 1024 * 2);
  bf16* Wq2t   = (bf16*)alloc((size_t)1024 * 1024 * 2);
  bf16* Wk2t   = (bf16*)alloc((size_t)1024 * 1024 * 2);
  bf16* Wv2t   = (bf16*)alloc((size_t)1024 * 1024 * 2);
  bf16* Wo1t   = (bf16*)alloc((size_t)1024 * 1024 * 2);
  bf16* Wo2t   = (bf16*)alloc((size_t)1024 * 1024 * 2);
  bf16* W1t    = (bf16*)alloc((size_t)4096 * 1024 * 2);
  bf16* W2t    = (bf16*)alloc((size_t)4096 * 1024 * 2);
  float* qkb1  = (float*)alloc(2048 * 4);
  float* sbq2  = (float*)alloc(1024 * 4);
  char*  S     = alloc((size_t)64 * 1024 * 1024);
  float* rbuf  = (float*)alloc((size_t)8 * 1024 * 1024 * 4);
  float* xnf   = (float*)alloc((size_t)8 * 1024 * 1024 * 4);
  bf16*  xnb   = (bf16*)alloc(ACT);

  bf16* q1   = (bf16*)(S);
  bf16* k1   = (bf16*)(S + ACT);
  bf16* vt1  = (bf16*)(S + 2 * ACT);   // [1024 dk_full][8192 tok]
  bf16* z1   = (bf16*)(S + 3 * ACT);
  bf16* hbuf = (bf16*)S;  // stage 3 reuse (64 MB)

  dim3 b256(256);
  dim3 b512(512);
  // prep: casts + weight packs
  cast_f2b_kernel<<<8192, b256, 0, stream>>>(x, xb, 2097152);
  cast_f2b_kernel<<<8192, b256, 0, stream>>>(enc, encb, 2097152);
  tpack_kernel<<<dim3(32, 2, 16), b256, 0, stream>>>(Wq1, Wqk1t, 1024, 64, 65536, 65536, QSC);
  tpack_kernel<<<dim3(32, 2, 16), b256, 0, stream>>>(Wk1, Wqk1t + 1048576, 1024, 64, 65536, 65536, 1.f);
  tpack_kernel<<<dim3(32, 2, 16), b256, 0, stream>>>(Wv1, Wv1t, 1024, 64, 65536, 65536, 1.f);
  tpack_kernel<<<dim3(32, 2, 16), b256, 0, stream>>>(Wq2, Wq2t, 1024, 64, 65536, 65536, QSC);
  tpack_kernel<<<dim3(32, 2, 16), b256, 0, stream>>>(Wk2, Wk2t, 1024, 64, 65536, 65536, 1.f);
  tpack_kernel<<<dim3(32, 2, 16), b256, 0, stream>>>(Wv2, Wv2t, 1024, 64, 65536, 65536, 1.f);
  tpack_kernel<<<dim3(32, 32, 1), b256, 0, stream>>>(Wo1, Wo1t, 1024, 1024, 0, 0, 1.f);
  tpack_kernel<<<dim3(32, 32, 1), b256, 0, stream>>>(Wo2, Wo2t, 1024, 1024, 0, 0, 1.f);
  tpack_kernel<<<dim3(32, 128, 1), b256, 0, stream>>>(W1, W1t, 1024, 4096, 0, 0, 1.f);
  tpack_kernel<<<dim3(128, 32, 1), b256, 0, stream>>>(W2, W2t, 4096, 1024, 0, 0, 1.f);
  bscale_kernel<<<4, b256, 0, stream>>>(bq1, qkb1, 1024, QSC);
  bscale_kernel<<<4, b256, 0, stream>>>(bk1, qkb1 + 1024, 1024, 1.f);
  bscale_kernel<<<4, b256, 0, stream>>>(bq2, sbq2, 1024, QSC);

  // stage 1: masked self-attention (QK fused N=2048; V^T as its own GEMM)
  gemm8<4><<<512, b512, 0, stream>>>(xb, Wqk1t, qkb1, nullptr, q1, 8192, 2048, 1024);
  gemm8<6><<<256, b512, 0, stream>>>(Wv1t, xb, bv1, nullptr, vt1, 1024, 8192, 1024);
  attn_kernel<true><<<1024, b256, 0, stream>>>(q1, k1, vt1, z1);
  gemm8<1><<<256, b512, 0, stream>>>(z1, Wo1t, bo1, x, rbuf, 8192, 1024, 1024);
  ln_kernel<<<8192, b256, 0, stream>>>(rbuf, g1, be1, xnf, xnb);

  // stage 2: cross-attention
  gemm8<0><<<256, b512, 0, stream>>>(xnb, Wq2t, sbq2, nullptr, q1, 8192, 1024, 1024);
  gemm8<0><<<256, b512, 0, stream>>>(encb, Wk2t, bk2, nullptr, k1, 8192, 1024, 1024);
  gemm8<6><<<256, b512, 0, stream>>>(Wv2t, encb, bv2, nullptr, vt1, 1024, 8192, 1024);
  attn_kernel<false><<<1024, b256, 0, stream>>>(q1, k1, vt1, z1);
  gemm8<1><<<256, b512, 0, stream>>>(z1, Wo2t, bo2, xnf, rbuf, 8192, 1024, 1024);
  ln_kernel<<<8192, b256, 0, stream>>>(rbuf, g2, be2, xnf, xnb);

  // stage 3: MLP (conv1d k=1 pair)
  gemm8<2><<<1024, b512, 0, stream>>>(xnb, W1t, b1, nullptr, hbuf, 8192, 4096, 1024);
  gemm8<1><<<256, b512, 0, stream>>>(hbuf, W2t, b2, xnf, rbuf, 8192, 1024, 4096);
  ln_kernel<<<8192, b256, 0, stream>>>(rbuf, g3, be3, (float*)d_out, nullptr);
}

// Round 17
// 566.060 us; speedup vs baseline: 1.0516x; 1.0516x over previous
//
#include <hip/hip_runtime.h>
#include <hip/hip_bf16.h>

typedef __bf16 bf16;
typedef __bf16 bf16x8 __attribute__((ext_vector_type(8)));
typedef __bf16 bf16x4v __attribute__((ext_vector_type(4)));
typedef float f32x4 __attribute__((ext_vector_type(4)));
typedef unsigned int u32;
typedef u32 u32x4 __attribute__((ext_vector_type(4)));

#define DEV static __device__ __forceinline__
#define SB0 __builtin_amdgcn_sched_barrier(0)
#define BAR __builtin_amdgcn_s_barrier()
#define LGKM0 asm volatile("s_waitcnt lgkmcnt(0)" ::: "memory")
#define LGKM8 asm volatile("s_waitcnt lgkmcnt(8)" ::: "memory")
#define VM4 asm volatile("s_waitcnt vmcnt(4)" ::: "memory")
#define PRIO1 __builtin_amdgcn_s_setprio(1)
#define PRIO0 __builtin_amdgcn_s_setprio(0)

DEV void gll16(const void* g, void* l) {
  __builtin_amdgcn_global_load_lds((__attribute__((address_space(1))) void*)g,
                                   (__attribute__((address_space(3))) void*)l,
                                   16, 0, 0);
}

DEV bf16 tobf(float f) { return (bf16)f; }

DEV u32 cvtpk(float lo, float hi) {
  u32 r;
  asm("v_cvt_pk_bf16_f32 %0, %1, %2" : "=v"(r) : "v"(lo), "v"(hi));
  return r;
}

// ---------------- cast f32 -> bf16 (x4 vectorized) ----------------
__global__ void cast_f2b_kernel(const float* __restrict__ in, bf16* __restrict__ out, int n4) {
  int i = blockIdx.x * 256 + threadIdx.x;
  if (i < n4) {
    const float4 v = ((const float4*)in)[i];
    bf16x4v o;
    o[0] = tobf(v.x); o[1] = tobf(v.y); o[2] = tobf(v.z); o[3] = tobf(v.w);
    ((bf16x4v*)out)[i] = o;
  }
}

// ------------- transpose-pack: out[N][K] bf16 = in[K][N] f32 * scale -------------
__global__ __launch_bounds__(256)
void tpack_kernel(const float* __restrict__ in, bf16* __restrict__ out,
                  int K, int N, int in_hs, int out_hs, float scale) {
  __shared__ float tile[32][33];
  const int k0 = blockIdx.x << 5, n0 = blockIdx.y << 5;
  const float* ip = in + (size_t)blockIdx.z * in_hs;
  bf16* op = out + (size_t)blockIdx.z * out_hs;
  const int tx = threadIdx.x & 31, ty = threadIdx.x >> 5;
#pragma unroll
  for (int r = 0; r < 4; ++r)
    tile[ty * 4 + r][tx] = ip[(size_t)(k0 + ty * 4 + r) * N + n0 + tx];
  __syncthreads();
#pragma unroll
  for (int r = 0; r < 4; ++r)
    op[(size_t)(n0 + ty * 4 + r) * K + k0 + tx] = tobf(tile[tx][ty * 4 + r] * scale);
}

// ---------------- bias scale copy ----------------
__global__ void bscale_kernel(const float* __restrict__ in, float* __restrict__ out, int n, float s) {
  int i = blockIdx.x * 256 + threadIdx.x;
  if (i < n) out[i] = in[i] * s;
}

// 2D L2 group swizzle (4x4 blocks per group) after XCD chunking.
DEV void tile_map(int bid, int nwg, int nbx, int& tm, int& tn) {
  bid = (bid & 7) * (nwg >> 3) + (bid >> 3);     // XCD chunk
  const int gid = bid >> 4, g4 = bid & 15;
  const int gpr = nbx >> 2;
  tm = ((gid / gpr) << 2) | (g4 >> 2);
  tn = ((gid % gpr) << 2) | (g4 & 3);
}

// Per-lane swizzled LDS read base (bits 4-6 XOR is lane-constant since all
// fragment rows are R0 + l15 with R0 % 16 == 0):
DEV int lane_base(int l15, int l4, int kk) {
  return (l15 << 7) + (((kk << 6) | (l4 << 4)) ^ ((l15 & 7) << 4));
}

// =====================================================================
// gemm8: BM=256 BN=128 BK=64, 512 thr = 8 waves (4M x 2N),
// 3 LDS buffers (144 KiB -> 1 block/CU), counted vmcnt(6), setprio.
// EPI 0: bf16 acc+bias(col)     1: bf16 acc+bias+resid(f32)
// EPI 6: bf16 acc+bias(ROW)     7: bf16 acc+bias+resid(bf16)
// =====================================================================
template<int EPI>
__global__ __launch_bounds__(512, 1)
void gemm8(const bf16* __restrict__ A, const bf16* __restrict__ W,
           const float* __restrict__ bias, const void* __restrict__ resid,
           void* __restrict__ outv, int M, int N, int K) {
  __shared__ bf16 sA[3][256 * 64];
  __shared__ bf16 sB[3][128 * 64];
  const int nbx = N >> 7;
  const int nwg = (M >> 8) * nbx;
  int tm, tn;
  tile_map((int)blockIdx.x, nwg, nbx, tm, tn);
  const int tid = threadIdx.x;
  const int lane = tid & 63;
  const int w = tid >> 6;
  const int wr = w >> 1, wc = w & 1;           // 4M x 2N waves
  const int l15 = lane & 15, l4 = lane >> 4;

  const bf16* Abase = A + (size_t)(tm * 256) * K;
  const bf16* Bbase = W + (size_t)(tn * 128) * K;

  const bf16* gAsrc[4];
  int loffA[4];
#pragma unroll
  for (int j = 0; j < 4; ++j) {
    int g = tid + (j << 9);
    int row = g >> 3;
    int sc = ((g & 7) ^ (row & 7)) << 3;
    gAsrc[j] = Abase + (size_t)row * K + sc;
    loffA[j] = g << 4;
  }
  const bf16* gBsrc[2];
  int loffB[2];
#pragma unroll
  for (int j = 0; j < 2; ++j) {
    int g = tid + (j << 9);
    int row = g >> 3;
    int sc = ((g & 7) ^ (row & 7)) << 3;
    gBsrc[j] = Bbase + (size_t)row * K + sc;
    loffB[j] = g << 4;
  }

  int obA[2], obB[2];
#pragma unroll
  for (int kk = 0; kk < 2; ++kk) {
    obA[kk] = wr * 8192 + lane_base(l15, l4, kk);
    obB[kk] = wc * 8192 + lane_base(l15, l4, kk);
  }

  f32x4 acc[4][4] = {};
  const int nt = K >> 6;

  auto stageA = [&](int buf, int t) {
    const int db = buf << 15;                   // sA buffer stride 32768 B
    const size_t so = (size_t)t << 6;
#pragma unroll
    for (int j = 0; j < 4; ++j) gll16(gAsrc[j] + so, (char*)sA + db + loffA[j]);
  };
  auto stageB = [&](int buf, int t) {
    const int db = buf << 14;                   // sB buffer stride 16384 B
    const size_t so = (size_t)t << 6;
#pragma unroll
    for (int j = 0; j < 2; ++j) gll16(gBsrc[j] + so, (char*)sB + db + loffB[j]);
  };

  stageA(0, 0); stageB(0, 0);
  stageA(1, 1 < nt ? 1 : 0); stageB(1, 1 < nt ? 1 : 0);
  SB0;
  asm volatile("s_waitcnt vmcnt(6)" ::: "memory");
  BAR;

  int c = 0;
  for (int t = 0; t < nt; ++t) {
    const int sb = (c >= 1) ? c - 1 : 2;       // (t+2)%3
    const int ts = (t + 2 < nt) ? t + 2 : nt - 1;
    const int aOff = c << 15, bOff = c << 14;
    bf16x8 af[4][2], bfr[4][2];
#pragma unroll
    for (int mi = 0; mi < 4; ++mi)
#pragma unroll
      for (int kk = 0; kk < 2; ++kk)
        af[mi][kk] = *(const bf16x8*)((const char*)sA + aOff + obA[kk] + (mi << 11));
#pragma unroll
    for (int ni = 0; ni < 2; ++ni)
#pragma unroll
      for (int kk = 0; kk < 2; ++kk)
        bfr[ni][kk] = *(const bf16x8*)((const char*)sB + bOff + obB[kk] + (ni << 11));
    stageA(sb, ts);
    SB0; BAR; LGKM0; SB0; PRIO1;
#pragma unroll
    for (int mi = 0; mi < 4; ++mi)
#pragma unroll
      for (int ni = 0; ni < 2; ++ni)
#pragma unroll
        for (int kk = 0; kk < 2; ++kk)
          acc[mi][ni] = __builtin_amdgcn_mfma_f32_16x16x32_bf16(af[mi][kk], bfr[ni][kk],
                                                                acc[mi][ni], 0, 0, 0);
    PRIO0; SB0; BAR;
#pragma unroll
    for (int ni = 2; ni < 4; ++ni)
#pragma unroll
      for (int kk = 0; kk < 2; ++kk)
        bfr[ni][kk] = *(const bf16x8*)((const char*)sB + bOff + obB[kk] + (ni << 11));
    stageB(sb, ts);
    SB0;
    asm volatile("s_waitcnt vmcnt(6)" ::: "memory");
    BAR; LGKM0; SB0; PRIO1;
#pragma unroll
    for (int mi = 0; mi < 4; ++mi)
#pragma unroll
      for (int ni = 2; ni < 4; ++ni)
#pragma unroll
        for (int kk = 0; kk < 2; ++kk)
          acc[mi][ni] = __builtin_amdgcn_mfma_f32_16x16x32_bf16(af[mi][kk], bfr[ni][kk],
                                                                acc[mi][ni], 0, 0, 0);
    PRIO0; SB0; BAR;
    c = (c == 2) ? 0 : c + 1;
  }

  const int row0 = tm * 256 + wr * 64 + (l4 << 2);
  const int col0 = tn * 128 + wc * 64 + l15;
#pragma unroll
  for (int ni = 0; ni < 4; ++ni) {
    const int col = col0 + (ni << 4);
    const float bv = (EPI == 6) ? 0.f : bias[col];
#pragma unroll
    for (int mi = 0; mi < 4; ++mi) {
      const int rr = row0 + (mi << 4);
      f32x4 v = acc[mi][ni];
      if (EPI == 0) {
        bf16* out = (bf16*)outv;
#pragma unroll
        for (int r = 0; r < 4; ++r) out[(size_t)(rr + r) * N + col] = tobf(v[r] + bv);
      } else if (EPI == 1) {       // bf16 out = acc + bias + resid(f32)
        bf16* out = (bf16*)outv;
        const float* rp = (const float*)resid;
#pragma unroll
        for (int r = 0; r < 4; ++r) {
          size_t idx = (size_t)(rr + r) * N + col;
          out[idx] = tobf(v[r] + bv + rp[idx]);
        }
      } else if (EPI == 7) {       // bf16 out = acc + bias + resid(bf16)
        bf16* out = (bf16*)outv;
        const bf16* rp = (const bf16*)resid;
#pragma unroll
        for (int r = 0; r < 4; ++r) {
          size_t idx = (size_t)(rr + r) * N + col;
          out[idx] = tobf(v[r] + bv + (float)rp[idx]);
        }
      } else { // EPI 6: row-indexed bias (V^T GEMM)
        bf16* out = (bf16*)outv;
        const float4 bq = *(const float4*)(bias + rr);
        const float br[4] = {bq.x, bq.y, bq.z, bq.w};
#pragma unroll
        for (int r = 0; r < 4; ++r) out[(size_t)(rr + r) * N + col] = tobf(v[r] + br[r]);
      }
    }
  }
}

// =====================================================================
// gemmP — 8-phase GEMM (r15 form, af-reuse) for QK and MLP1: BM=BN=256,
// BK=64, 512 thr = 8 waves (2M x 4N). Measured slightly faster than gemm8
// on these shapes (92-95 vs 97 us) despite residual spill traffic.
// EPI 2: relu   4: fused QK segs (N=2048, both rowmajor)
// =====================================================================
template<int EPI>
__global__ __launch_bounds__(512, 1)
void gemmP(const bf16* __restrict__ A, const bf16* __restrict__ W,
           const float* __restrict__ bias, const float* __restrict__ resid,
           void* __restrict__ outv, int M, int N, int K) {
  __shared__ bf16 sA[2][2][128 * 64];   // [buf][half][.]
  __shared__ bf16 sB[2][2][128 * 64];
  const int nbx = N >> 8;
  const int nwg = (M >> 8) * nbx;
  int tm, tn;
  tile_map((int)blockIdx.x, nwg, nbx, tm, tn);
  const int tid = threadIdx.x;
  const int lane = tid & 63;
  const int w = tid >> 6;
  const int wr = w >> 2, wc = w & 3;           // 2M x 4N waves
  const int l15 = lane & 15, l4 = lane >> 4;

  const bf16* Abase = A + (size_t)(tm * 256) * K;
  const bf16* Bbase = W + (size_t)(tn * 256) * K;

  const bf16* gAsrc[2], *gBsrc[2];
  int loff[2];
#pragma unroll
  for (int j = 0; j < 2; ++j) {
    int g = tid + (j << 9);
    int row = g >> 3;
    int sc = ((g & 7) ^ (row & 7)) << 3;
    gAsrc[j] = Abase + (size_t)row * K + sc;
    gBsrc[j] = Bbase + (size_t)row * K + sc;
    loff[j] = g << 4;
  }

  int obA[2], obB[2];
#pragma unroll
  for (int kk = 0; kk < 2; ++kk) {
    obA[kk] = wr * 16384 + lane_base(l15, l4, kk);
    obB[kk] = (wc >> 1) * 16384 + ((wc & 1) << 13) + lane_base(l15, l4, kk);
  }

  f32x4 acc[8][4] = {};
  const int nt = K >> 6;
  const int nit = nt >> 1;

  auto stageA2 = [&](int buf, int h, int t) {
    const int db = (buf << 15) + (h << 14);
    const size_t so = (size_t)(h * 128) * K + ((size_t)t << 6);
#pragma unroll
    for (int j = 0; j < 2; ++j) gll16(gAsrc[j] + so, (char*)sA + db + loff[j]);
  };
  auto stageB2 = [&](int buf, int h, int t) {
    const int db = (buf << 15) + (h << 14);
    const size_t so = (size_t)(h * 128) * K + ((size_t)t << 6);
#pragma unroll
    for (int j = 0; j < 2; ++j) gll16(gBsrc[j] + so, (char*)sB + db + loff[j]);
  };

  stageA2(0, 0, 0);
  stageA2(0, 1, 0);
  stageB2(0, 0, 0);
  stageB2(0, 1, 0);
  stageB2(1, 0, 1);
  stageB2(1, 1, 1);
  SB0; VM4; BAR;

  for (int it = 0; it < nit; ++it) {
    const int tod = 2 * it + 1;
    const int ts2 = (2 * it + 2 < nt) ? 2 * it + 2 : nt - 1;
    const int ts3 = (2 * it + 3 < nt) ? 2 * it + 3 : nt - 1;

    auto doTile = [&](int b, int ab, int at, int bb, int bt) {
      const int BO = b << 15;
      bf16x8 af[4][2], b01[2][2], b23[2][2];
      // ---- phase 1: Mlo x N01 (12 reads; stage Ah0) ----
#pragma unroll
      for (int mi = 0; mi < 4; ++mi)
#pragma unroll
        for (int kk = 0; kk < 2; ++kk)
          af[mi][kk] = *(const bf16x8*)((const char*)sA + BO + obA[kk] + (mi << 11));
#pragma unroll
      for (int ni = 0; ni < 2; ++ni)
#pragma unroll
        for (int kk = 0; kk < 2; ++kk)
          b01[ni][kk] = *(const bf16x8*)((const char*)sB + BO + obB[kk] + (ni << 11));
      stageA2(ab, 0, at);
      SB0; LGKM8; BAR; LGKM0; SB0; PRIO1;
#pragma unroll
      for (int mi = 0; mi < 4; ++mi)
#pragma unroll
        for (int ni = 0; ni < 2; ++ni)
#pragma unroll
          for (int kk = 0; kk < 2; ++kk)
            acc[mi][ni] = __builtin_amdgcn_mfma_f32_16x16x32_bf16(af[mi][kk], b01[ni][kk],
                                                                  acc[mi][ni], 0, 0, 0);
      PRIO0; SB0; BAR;
      // ---- phase 2: Mlo x N23 (4 reads; stage Ah1) ----
#pragma unroll
      for (int ni = 0; ni < 2; ++ni)
#pragma unroll
        for (int kk = 0; kk < 2; ++kk)
          b23[ni][kk] = *(const bf16x8*)((const char*)sB + BO + obB[kk] + 4096 + (ni << 11));
      stageA2(ab, 1, at);
      SB0; BAR; LGKM0; SB0; PRIO1;
#pragma unroll
      for (int mi = 0; mi < 4; ++mi)
#pragma unroll
        for (int ni = 0; ni < 2; ++ni)
#pragma unroll
          for (int kk = 0; kk < 2; ++kk)
            acc[mi][ni + 2] = __builtin_amdgcn_mfma_f32_16x16x32_bf16(af[mi][kk], b23[ni][kk],
                                                                      acc[mi][ni + 2], 0, 0, 0);
      PRIO0; SB0; BAR;
      // ---- phase 3: Mhi x N01 (8 reads -> af reuse; stage Bh0) ----
#pragma unroll
      for (int mi = 0; mi < 4; ++mi)
#pragma unroll
        for (int kk = 0; kk < 2; ++kk)
          af[mi][kk] = *(const bf16x8*)((const char*)sA + BO + obA[kk] + 8192 + (mi << 11));
      stageB2(bb, 0, bt);
      SB0; BAR; LGKM0; SB0; PRIO1;
#pragma unroll
      for (int mi = 0; mi < 4; ++mi)
#pragma unroll
        for (int ni = 0; ni < 2; ++ni)
#pragma unroll
          for (int kk = 0; kk < 2; ++kk)
            acc[mi + 4][ni] = __builtin_amdgcn_mfma_f32_16x16x32_bf16(af[mi][kk], b01[ni][kk],
                                                                      acc[mi + 4][ni], 0, 0, 0);
      PRIO0; SB0; BAR;
      // ---- phase 4: Mhi x N23 (0 reads; stage Bh1; GATE vmcnt(4)) ----
      stageB2(bb, 1, bt);
      SB0; VM4; BAR; PRIO1;
#pragma unroll
      for (int mi = 0; mi < 4; ++mi)
#pragma unroll
        for (int ni = 0; ni < 2; ++ni)
#pragma unroll
          for (int kk = 0; kk < 2; ++kk)
            acc[mi + 4][ni + 2] = __builtin_amdgcn_mfma_f32_16x16x32_bf16(af[mi][kk], b23[ni][kk],
                                                                          acc[mi + 4][ni + 2], 0, 0, 0);
      PRIO0; SB0; BAR;
    };

    doTile(0, 1, tod, 0, ts2);
    doTile(1, 0, ts2, 1, ts3);
  }

  const int row0 = tm * 256 + wr * 128 + (l4 << 2);
  const int col0 = tn * 256 + wc * 64 + l15;
#pragma unroll
  for (int ni = 0; ni < 4; ++ni) {
    const int col = col0 + (ni << 4);
    const float bv = bias ? bias[col] : 0.f;
#pragma unroll
    for (int mi = 0; mi < 8; ++mi) {
      const int rr = row0 + (mi << 4);
      f32x4 v = acc[mi][ni];
      if (EPI == 2) {
        bf16* out = (bf16*)outv;
#pragma unroll
        for (int r = 0; r < 4; ++r) out[(size_t)(rr + r) * N + col] = tobf(fmaxf(v[r] + bv, 0.f));
      } else { // EPI 4: fused QK segments (1024-col each), both rowmajor
        bf16* out = (bf16*)outv;
        const int seg = col >> 10;
        const int cc = col & 1023;
        bf16* qout = out + (size_t)seg * 8388608;
#pragma unroll
        for (int r = 0; r < 4; ++r) qout[(size_t)(rr + r) * 1024 + cc] = tobf(v[r] + bv);
      }
    }
  }
}

// =====================================================================
// Attention (unchanged): swapped-QK^T, defer-max, in-register P.
// V^T layout [1024 dk_full][8192 tok].
// =====================================================================
template<bool MASKED>
__global__ __launch_bounds__(256, 2)
void attn_kernel(const bf16* __restrict__ Qp, const bf16* __restrict__ Kp,
                 const bf16* __restrict__ Vt, bf16* __restrict__ Z) {
  __shared__ bf16 sK[2][64 * 64];
  __shared__ bf16 sV[2][64 * 64];
  const int Lk = 1024;
  const int d = blockIdx.x;
  const int bh = d & 127, qb = d >> 7;
  const int b = bh >> 4, h = bh & 15;
  const int q0 = qb << 7;
  const int tid = threadIdx.x, lane = tid & 63, w = tid >> 6;
  const int l15 = lane & 15, l4 = lane >> 4;

  const bf16* Qb = Qp + ((size_t)(b * 1024 + q0 + w * 32)) * 1024 + h * 64;
  bf16x8 qf[2][2];
#pragma unroll
  for (int mi = 0; mi < 2; ++mi)
#pragma unroll
    for (int kk = 0; kk < 2; ++kk)
      qf[mi][kk] = *(const bf16x8*)(Qb + (size_t)((mi << 4) + l15) * 1024 + (kk << 5) + (l4 << 3));

  f32x4 o[4][2] = {};
  float Mr[2] = {-1e30f, -1e30f}, LrP[2] = {0.f, 0.f};

  const bf16* Kb = Kp + ((size_t)b * Lk) * 1024 + h * 64;
  const bf16* Vb = Vt + (size_t)(h * 64) * 8192 + b * 1024;

  auto stage = [&](int buf, int t, bool withV) {
    const int kv0 = t << 6;
#pragma unroll
    for (int j = 0; j < 2; ++j) {
      int g = tid + (j << 8);
      int r = g >> 3;
      int sc = ((g & 7) ^ (r & 7)) << 3;
      gll16(Kb + (size_t)(kv0 + r) * 1024 + sc, &sK[buf][g << 3]);
      if (withV) gll16(Vb + (size_t)r * 8192 + kv0 + sc, &sV[buf][g << 3]);
    }
  };
  auto needPV = [&](int t) -> bool { return !MASKED || ((t << 6) < q0 + 128); };

  const int NT = Lk >> 6;
  stage(0, 0, true);
  __syncthreads();
  int cur = 0;

  for (int t = 0; t < NT; ++t) {
    if (t + 1 < NT) stage(cur ^ 1, t + 1, needPV(t + 1));
    const int kv0 = t << 6;

    f32x4 s[4][2] = {};
#pragma unroll
    for (int n = 0; n < 4; ++n) {
      bf16x8 kf[2];
#pragma unroll
      for (int kk = 0; kk < 2; ++kk) {
        int r = (n << 4) + l15;
        int off = (r << 7) + (kk << 6) + (l4 << 4);
        off ^= (r & 7) << 4;
        kf[kk] = *(const bf16x8*)((const char*)sK[cur] + off);
      }
#pragma unroll
      for (int mi = 0; mi < 2; ++mi)
#pragma unroll
        for (int kk = 0; kk < 2; ++kk)
          s[n][mi] = __builtin_amdgcn_mfma_f32_16x16x32_bf16(kf[kk], qf[mi][kk],
                                                             s[n][mi], 0, 0, 0);
    }

#pragma unroll
    for (int mi = 0; mi < 2; ++mi) {
      float lmax = s[0][mi][0];
#pragma unroll
      for (int n = 0; n < 4; ++n)
#pragma unroll
        for (int r = 0; r < 4; ++r) lmax = fmaxf(lmax, s[n][mi][r]);
      const bool need = (t == 0) || !__all(lmax <= Mr[mi] + 8.f);
      if (need) {
        float tmx = fmaxf(lmax, __shfl_xor(lmax, 16, 64));
        tmx = fmaxf(tmx, __shfl_xor(tmx, 32, 64));
        const float Mn = fmaxf(Mr[mi], tmx);
        const float al = exp2f(Mr[mi] - Mn);
        LrP[mi] *= al;
        Mr[mi] = Mn;
#pragma unroll
        for (int r = 0; r < 4; ++r) {
          float a = __shfl(al, (l4 << 2) + r, 64);
#pragma unroll
          for (int nd = 0; nd < 4; ++nd) o[nd][mi][r] *= a;
        }
      }
      float rs = 0.f;
#pragma unroll
      for (int n = 0; n < 4; ++n)
#pragma unroll
        for (int r = 0; r < 4; ++r) {
          float p = exp2f(s[n][mi][r] - Mr[mi]);
          s[n][mi][r] = p;
          rs += p;
        }
      LrP[mi] += rs;
    }

    if (needPV(t)) {
      const bool needMask = MASKED && (kv0 + 63 > q0 + (w << 5));
      bf16x8 pa[2][2];
#pragma unroll
      for (int mi = 0; mi < 2; ++mi) {
        u32 D0[4], D1[4];
        const int qg = q0 + (w << 5) + (mi << 4) + l15;
#pragma unroll
        for (int n = 0; n < 4; ++n) {
          float pv[4];
#pragma unroll
          for (int r = 0; r < 4; ++r) {
            float p = s[n][mi][r];
            if (needMask) {
              int cg = kv0 + (n << 4) + (l4 << 2) + r;
              if (cg > qg) p = 0.f;
            }
            pv[r] = p;
          }
          D0[n] = cvtpk(pv[0], pv[1]);
          D1[n] = cvtpk(pv[2], pv[3]);
        }
        const int src = l15 + ((lane & 16) << 1);
#pragma unroll
        for (int kk = 0; kk < 2; ++kk) {
          u32 v0 = (lane & 32) ? D0[2 * kk + 1] : D0[2 * kk];
          u32 v1 = (lane & 32) ? D1[2 * kk + 1] : D1[2 * kk];
          u32x4 tw;
          tw[0] = (u32)__shfl((int)v0, src, 64);
          tw[1] = (u32)__shfl((int)v1, src, 64);
          tw[2] = (u32)__shfl((int)v0, src + 16, 64);
          tw[3] = (u32)__shfl((int)v1, src + 16, 64);
          pa[mi][kk] = __builtin_bit_cast(bf16x8, tw);
        }
      }
#pragma unroll
      for (int nd = 0; nd < 4; ++nd) {
        bf16x8 vf[2];
#pragma unroll
        for (int kk = 0; kk < 2; ++kk) {
          int r = (nd << 4) + l15;
          int off = (r << 7) + (kk << 6) + (l4 << 4);
          off ^= (r & 7) << 4;
          vf[kk] = *(const bf16x8*)((const char*)sV[cur] + off);
        }
#pragma unroll
        for (int mi = 0; mi < 2; ++mi)
#pragma unroll
          for (int kk = 0; kk < 2; ++kk)
            o[nd][mi] = __builtin_amdgcn_mfma_f32_16x16x32_bf16(pa[mi][kk], vf[kk],
                                                                o[nd][mi], 0, 0, 0);
      }
    }
    __syncthreads();
    cur ^= 1;
  }

  float inv[2][4];
#pragma unroll
  for (int mi = 0; mi < 2; ++mi) {
    float l = LrP[mi];
    l += __shfl_xor(l, 16, 64);
    l += __shfl_xor(l, 32, 64);
    const float il = 1.f / l;
#pragma unroll
    for (int r = 0; r < 4; ++r) inv[mi][r] = __shfl(il, (l4 << 2) + r, 64);
  }
  bf16* Zb = Z + ((size_t)(b * 1024 + q0 + w * 32)) * 1024 + h * 64;
#pragma unroll
  for (int nd = 0; nd < 4; ++nd)
#pragma unroll
    for (int mi = 0; mi < 2; ++mi)
#pragma unroll
      for (int r = 0; r < 4; ++r)
        Zb[(size_t)((mi << 4) + (l4 << 2) + r) * 1024 + (nd << 4) + l15] =
            tobf(o[nd][mi][r] * inv[mi][r]);
}

// ---------- LayerNorm over D=1024, bf16 input; f32 and/or bf16 out ----------
__global__ __launch_bounds__(256)
void lnb_kernel(const bf16* __restrict__ in, const float* __restrict__ gw,
                const float* __restrict__ bw, float* __restrict__ outf,
                bf16* __restrict__ outb) {
  const int row = blockIdx.x, tid = threadIdx.x;
  const size_t base = (size_t)row << 10;
  const bf16x4v v4 = *(const bf16x4v*)(in + base + tid * 4);
  float v0 = (float)v4[0], v1 = (float)v4[1], v2 = (float)v4[2], v3 = (float)v4[3];
  float s = v0 + v1 + v2 + v3;
  float ss = v0 * v0 + v1 * v1 + v2 * v2 + v3 * v3;
#pragma unroll
  for (int d = 1; d < 64; d <<= 1) { s += __shfl_xor(s, d, 64); ss += __shfl_xor(ss, d, 64); }
  __shared__ float red[8];
  const int w = tid >> 6;
  if ((tid & 63) == 0) { red[w] = s; red[4 + w] = ss; }
  __syncthreads();
  s = red[0] + red[1] + red[2] + red[3];
  ss = red[4] + red[5] + red[6] + red[7];
  const float mu = s * (1.f / 1024.f);
  const float var = ss * (1.f / 1024.f) - mu * mu;
  const float rstd = rsqrtf(var + 1e-5f);
  const float4 g4 = *(const float4*)(gw + tid * 4);
  const float4 b4 = *(const float4*)(bw + tid * 4);
  const float o0 = (v0 - mu) * rstd * g4.x + b4.x;
  const float o1 = (v1 - mu) * rstd * g4.y + b4.y;
  const float o2 = (v2 - mu) * rstd * g4.z + b4.z;
  const float o3 = (v3 - mu) * rstd * g4.w + b4.w;
  if (outf) { float4 of; of.x = o0; of.y = o1; of.z = o2; of.w = o3;
              *(float4*)(outf + base + tid * 4) = of; }
  if (outb) { bf16x4v ob; ob[0] = tobf(o0); ob[1] = tobf(o1); ob[2] = tobf(o2); ob[3] = tobf(o3);
              *(bf16x4v*)(outb + base + tid * 4) = ob; }
}

// =====================================================================
extern "C" void kernel_launch(void* const* d_in, const int* in_sizes, int n_in,
                              void* d_out, int out_size, void* d_ws, size_t ws_size,
                              hipStream_t stream) {
  const float* x   = (const float*)d_in[0];
  const float* enc = (const float*)d_in[1];
  const float* Wq1 = (const float*)d_in[2];
  const float* bq1 = (const float*)d_in[3];
  const float* Wk1 = (const float*)d_in[4];
  const float* bk1 = (const float*)d_in[5];
  const float* Wv1 = (const float*)d_in[6];
  const float* bv1 = (const float*)d_in[7];
  const float* Wo1 = (const float*)d_in[8];
  const float* bo1 = (const float*)d_in[9];
  const float* Wq2 = (const float*)d_in[10];
  const float* bq2 = (const float*)d_in[11];
  const float* Wk2 = (const float*)d_in[12];
  const float* bk2 = (const float*)d_in[13];
  const float* Wv2 = (const float*)d_in[14];
  const float* bv2 = (const float*)d_in[15];
  const float* Wo2 = (const float*)d_in[16];
  const float* bo2 = (const float*)d_in[17];
  const float* W1  = (const float*)d_in[18];
  const float* b1  = (const float*)d_in[19];
  const float* W2  = (const float*)d_in[20];
  const float* b2  = (const float*)d_in[21];
  const float* g1  = (const float*)d_in[22];
  const float* be1 = (const float*)d_in[23];
  const float* g2  = (const float*)d_in[24];
  const float* be2 = (const float*)d_in[25];
  const float* g3  = (const float*)d_in[26];
  const float* be3 = (const float*)d_in[27];

  char* ws = (char*)d_ws;
  size_t off = 0;
  auto alloc = [&](size_t bytes) { char* p = ws + off; off += (bytes + 255) & ~(size_t)255; return p; };
  const size_t ACT = (size_t)8 * 1024 * 1024 * 2;  // 16 MB: bf16 [8192][1024]
  const float QSC = 0.125f * 1.44269504088896f;    // fold 1/sqrt(DK) * log2(e)

  bf16* xb     = (bf16*)alloc(ACT);
  bf16* encb   = (bf16*)alloc(ACT);
  bf16* Wqk1t  = (bf16*)alloc((size_t)2048 * 1024 * 2);  // [Wq1|Wk1]^T
  bf16* Wv1t   = (bf16*)alloc((size_t)1024 * 1024 * 2);
  bf16* Wq2t   = (bf16*)alloc((size_t)1024 * 1024 * 2);
  bf16* Wk2t   = (bf16*)alloc((size_t)1024 * 1024 * 2);
  bf16* Wv2t   = (bf16*)alloc((size_t)1024 * 1024 * 2);
  bf16* Wo1t   = (bf16*)alloc((size_t)1024 * 1024 * 2);
  bf16* Wo2t   = (bf16*)alloc((size_t)1024 * 1024 * 2);
  bf16* W1t    = (bf16*)alloc((size_t)4096 * 1024 * 2);
  bf16* W2t    = (bf16*)alloc((size_t)4096 * 1024 * 2);
  float* qkb1  = (float*)alloc(2048 * 4);
  float* sbq2  = (float*)alloc(1024 * 4);
  char*  S     = alloc((size_t)64 * 1024 * 1024);
  bf16*  rbufb = (bf16*)alloc(ACT);
  bf16*  xnb1  = (bf16*)alloc(ACT);
  bf16*  xnb2  = (bf16*)alloc(ACT);

  bf16* q1   = (bf16*)(S);
  bf16* k1   = (bf16*)(S + ACT);
  bf16* vt1  = (bf16*)(S + 2 * ACT);   // [1024 dk_full][8192 tok]
  bf16* z1   = (bf16*)(S + 3 * ACT);
  bf16* hbuf = (bf16*)S;  // stage 3 reuse (64 MB)

  dim3 b256(256);
  dim3 b512(512);
  // prep: casts + weight packs
  cast_f2b_kernel<<<8192, b256, 0, stream>>>(x, xb, 2097152);
  cast_f2b_kernel<<<8192, b256, 0, stream>>>(enc, encb, 2097152);
  tpack_kernel<<<dim3(32, 2, 16), b256, 0, stream>>>(Wq1, Wqk1t, 1024, 64, 65536, 65536, QSC);
  tpack_kernel<<<dim3(32, 2, 16), b256, 0, stream>>>(Wk1, Wqk1t + 1048576, 1024, 64, 65536, 65536, 1.f);
  tpack_kernel<<<dim3(32, 2, 16), b256, 0, stream>>>(Wv1, Wv1t, 1024, 64, 65536, 65536, 1.f);
  tpack_kernel<<<dim3(32, 2, 16), b256, 0, stream>>>(Wq2, Wq2t, 1024, 64, 65536, 65536, QSC);
  tpack_kernel<<<dim3(32, 2, 16), b256, 0, stream>>>(Wk2, Wk2t, 1024, 64, 65536, 65536, 1.f);
  tpack_kernel<<<dim3(32, 2, 16), b256, 0, stream>>>(Wv2, Wv2t, 1024, 64, 65536, 65536, 1.f);
  tpack_kernel<<<dim3(32, 32, 1), b256, 0, stream>>>(Wo1, Wo1t, 1024, 1024, 0, 0, 1.f);
  tpack_kernel<<<dim3(32, 32, 1), b256, 0, stream>>>(Wo2, Wo2t, 1024, 1024, 0, 0, 1.f);
  tpack_kernel<<<dim3(32, 128, 1), b256, 0, stream>>>(W1, W1t, 1024, 4096, 0, 0, 1.f);
  tpack_kernel<<<dim3(128, 32, 1), b256, 0, stream>>>(W2, W2t, 4096, 1024, 0, 0, 1.f);
  bscale_kernel<<<4, b256, 0, stream>>>(bq1, qkb1, 1024, QSC);
  bscale_kernel<<<4, b256, 0, stream>>>(bk1, qkb1 + 1024, 1024, 1.f);
  bscale_kernel<<<4, b256, 0, stream>>>(bq2, sbq2, 1024, QSC);

  // stage 1: masked self-attention (QK fused N=2048; V^T as its own GEMM)
  gemmP<4><<<256, b512, 0, stream>>>(xb, Wqk1t, qkb1, nullptr, q1, 8192, 2048, 1024);
  gemm8<6><<<256, b512, 0, stream>>>(Wv1t, xb, bv1, nullptr, vt1, 1024, 8192, 1024);
  attn_kernel<true><<<1024, b256, 0, stream>>>(q1, k1, vt1, z1);
  gemm8<1><<<256, b512, 0, stream>>>(z1, Wo1t, bo1, x, rbufb, 8192, 1024, 1024);
  lnb_kernel<<<8192, b256, 0, stream>>>(rbufb, g1, be1, nullptr, xnb1);

  // stage 2: cross-attention
  gemm8<0><<<256, b512, 0, stream>>>(xnb1, Wq2t, sbq2, nullptr, q1, 8192, 1024, 1024);
  gemm8<0><<<256, b512, 0, stream>>>(encb, Wk2t, bk2, nullptr, k1, 8192, 1024, 1024);
  gemm8<6><<<256, b512, 0, stream>>>(Wv2t, encb, bv2, nullptr, vt1, 1024, 8192, 1024);
  attn_kernel<false><<<1024, b256, 0, stream>>>(q1, k1, vt1, z1);
  gemm8<7><<<256, b512, 0, stream>>>(z1, Wo2t, bo2, xnb1, rbufb, 8192, 1024, 1024);
  lnb_kernel<<<8192, b256, 0, stream>>>(rbufb, g2, be2, nullptr, xnb2);

  // stage 3: MLP (conv1d k=1 pair)
  gemmP<2><<<512, b512, 0, stream>>>(xnb2, W1t, b1, nullptr, hbuf, 8192, 4096, 1024);
  gemm8<7><<<256, b512, 0, stream>>>(hbuf, W2t, b2, xnb2, rbufb, 8192, 1024, 4096);
  lnb_kernel<<<8192, b256, 0, stream>>>(rbufb, g3, be3, (float*)d_out, nullptr);
}